// Round 8
// baseline (93.443 us; speedup 1.0000x reference)
//
#include <hip/hip_runtime.h>
#include <hip/hip_bf16.h>

// MLP_small_per_feature: per-feature MLP 1 -> 64 -> 64 -> 1, F=256, B=8192.
// v8 = v7 structure with the per-pass serial chain trimmed:
//  - epilogue: NO per-pass __shfl_xor pair (2 serial ds_bpermute ~250cy);
//    each lane ds_write's its 16-o partial to ob[feat*4+lg][row]; one-time
//    tail sums the 4 lane-group partials per row. (v5's idea, decoupled
//    from v5's fetch explosion which was scattered fp32 w2 -- fixed by w2p.)
//  - x staged pass-major xs[w][l15][pass] (stride 20, 16B-aligned); one
//    ds_read_b128 feeds 4 passes -> 4 LDS reads/wave instead of 16.
//  - w2 via packed bf16 fragment-major w2p (d_ws, 2 MB, L2-resident):
//    8 coalesced dwordx4 per wave.
//  - kRPB=256 -> 2048 blocks; launch_bounds(256,4) (v6 proved (256,8)
//    spills: VGPR=32, 1.3 GB scratch traffic -- never again).
//
// MFMA 16x16x32_bf16 layout (verified rounds 1-7, absmax 0.031):
//   A: row m = lane&15, k = (lane>>4)*8 + i
//   B: col n = lane&15, k = (lane>>4)*8 + i
//   C/D: col n = lane&15, row m = (lane>>4)*4 + r

namespace {

constexpr int kF = 256;
constexpr int kH = 64;
constexpr int kB = 8192;

constexpr int kFPB     = 4;               // features per block (one per wave)
constexpr int kRPB     = 256;             // rows per block
constexpr int kThreads = 256;             // 4 waves
constexpr int kFG      = kF / kFPB;       // 64 feature groups
constexpr int kRG      = kB / kRPB;       // 32 row groups
constexpr int kBlocks  = kFG * kRG;       // 2048
constexpr int kPasses  = kRPB / 16;       // 16
constexpr int kQ       = kPasses / 4;     // 4 ds_read_b128 granules

constexpr int kXPad = 20;                 // pass-dim stride (floats): 16B-aligned, 2-way banks
constexpr int kOB   = 264;                // ob row stride: 264%32==8 -> 2-way max (free)

using f32x4  = __attribute__((ext_vector_type(4))) float;
using bf16x4 = __attribute__((ext_vector_type(4))) __bf16;
using bf16x8 = __attribute__((ext_vector_type(8))) __bf16;

// ---- prep: pack w2 (fp32 [F][64][64]) -> bf16 fragment-major ----
// w2p elem offset ((f*8 + t*2+ks)*64 + lane)*8; lane l's fragment (t,ks) =
// w2[f][o=t*16+(l&15)][ks*32+(l>>4)*8 .. +8].
__global__ __launch_bounds__(256)
void pack_w2(const float* __restrict__ w2, __bf16* __restrict__ w2p)
{
  const int wid  = (int)threadIdx.x >> 6;
  const int lane = (int)threadIdx.x & 63;
  const int f    = (int)blockIdx.x * 4 + wid;
  const int l15  = lane & 15;
  const int lg   = lane >> 4;

  const float* w2f = w2 + (size_t)f * (kH * kH);
  #pragma unroll
  for (int t = 0; t < 4; ++t) {
    const int o = t * 16 + l15;
    #pragma unroll
    for (int ks = 0; ks < 2; ++ks) {
      const float* p = w2f + o * kH + ks * 32 + lg * 8;
      const f32x4 lo = *reinterpret_cast<const f32x4*>(p);
      const f32x4 hi = *reinterpret_cast<const f32x4*>(p + 4);
      const bf16x8 v = __builtin_shufflevector(
          __builtin_convertvector(lo, bf16x4),
          __builtin_convertvector(hi, bf16x4), 0, 1, 2, 3, 4, 5, 6, 7);
      *reinterpret_cast<bf16x8*>(
          w2p + (((size_t)f * 8 + t * 2 + ks) * 64 + lane) * 8) = v;
    }
  }
}

__global__ __launch_bounds__(kThreads, 4)
void mlp_pf_v8(const float* __restrict__ x,
               const float* __restrict__ w1,
               const float* __restrict__ b1,
               const __bf16* __restrict__ w2p,
               const float* __restrict__ b2,
               const float* __restrict__ w3,
               const float* __restrict__ b3,
               float* __restrict__ out)
{
  __shared__ float xs[kFPB][16][kXPad];   // 5.1 KB [feat][l15][pass]
  __shared__ float ob[kFPB * 4][kOB];     // 16.9 KB [feat*4+lg][row]

  const int tid  = (int)threadIdx.x;
  const int wid  = tid >> 6;
  const int lane = tid & 63;
  const int l15  = lane & 15;
  const int lg   = lane >> 4;

  const int fg = (int)blockIdx.x & (kFG - 1);  // consecutive blocks: same rows
  const int rg = (int)blockIdx.x >> 6;
  const int f  = fg * kFPB + wid;          // this wave's feature
  const int r0 = rg * kRPB;

  // ---- w2 fragments: 8 coalesced 16B loads/lane (L2-resident w2p) ----
  bf16x8 w2frag[4][2];
  {
    const __bf16* base = w2p + ((size_t)f * 8 * 64 + lane) * 8;
    #pragma unroll
    for (int t = 0; t < 4; ++t)
      #pragma unroll
      for (int ks = 0; ks < 2; ++ks)
        w2frag[t][ks] = *reinterpret_cast<const bf16x8*>(
            base + (size_t)(t * 2 + ks) * 64 * 8);
  }

  // ---- stage x tile (256 rows x 4 feats) -> pass-major LDS ----
  {
    const int rr = tid;                    // one row per thread
    const f32x4 v = *reinterpret_cast<const f32x4*>(
        x + (size_t)(r0 + rr) * kF + fg * kFPB);
    const int a = rr & 15, pp = rr >> 4;
    xs[0][a][pp] = v[0]; xs[1][a][pp] = v[1];
    xs[2][a][pp] = v[2]; xs[3][a][pp] = v[3];
  }

  // ---- per-wave params (tiny, L1/L2-resident) ----
  f32x4 w1v[2][2], b1v[2][2];
  #pragma unroll
  for (int ks = 0; ks < 2; ++ks) {
    const float* pw = w1 + f * kH + ks * 32 + lg * 8;
    const float* pb = b1 + f * kH + ks * 32 + lg * 8;
    w1v[ks][0] = *reinterpret_cast<const f32x4*>(pw);
    w1v[ks][1] = *reinterpret_cast<const f32x4*>(pw + 4);
    b1v[ks][0] = *reinterpret_cast<const f32x4*>(pb);
    b1v[ks][1] = *reinterpret_cast<const f32x4*>(pb + 4);
  }
  f32x4 b2c[4], w3v[4];
  #pragma unroll
  for (int t = 0; t < 4; ++t) {
    b2c[t] = *reinterpret_cast<const f32x4*>(b2 + f * kH + t * 16 + lg * 4);
    w3v[t] = *reinterpret_cast<const f32x4*>(w3 + f * kH + t * 16 + lg * 4);
  }

  __syncthreads();   // xs ready

  const f32x4 zero4 = {0.f, 0.f, 0.f, 0.f};
  float* obp = &ob[wid * 4 + lg][l15];     // per-pass dest: obp[p*16]

  #pragma unroll
  for (int q = 0; q < kQ; ++q) {
    // 4 passes' x values in one conflict-free ds_read_b128
    const f32x4 xq = *reinterpret_cast<const f32x4*>(&xs[wid][l15][q * 4]);

    #pragma unroll
    for (int j = 0; j < 4; ++j) {
      const int p = q * 4 + j;
      const float xv = xq[j];

      // ---- layer 1: h1 = relu(x*w1 + b1) -> bf16 B-fragments ----
      bf16x8 h1frag[2];
      #pragma unroll
      for (int ks = 0; ks < 2; ++ks) {
        f32x4 a = w1v[ks][0] * xv + b1v[ks][0];
        f32x4 b = w1v[ks][1] * xv + b1v[ks][1];
        a = __builtin_elementwise_max(a, zero4);
        b = __builtin_elementwise_max(b, zero4);
        h1frag[ks] = __builtin_shufflevector(
            __builtin_convertvector(a, bf16x4),
            __builtin_convertvector(b, bf16x4), 0, 1, 2, 3, 4, 5, 6, 7);
      }

      // ---- layer 2 (C init = b2) + layer 3 in-lane partial ----
      f32x4 p4 = zero4;
      #pragma unroll
      for (int t = 0; t < 4; ++t) {
        f32x4 acc = __builtin_amdgcn_mfma_f32_16x16x32_bf16(
            w2frag[t][0], h1frag[0], b2c[t], 0, 0, 0);
        acc = __builtin_amdgcn_mfma_f32_16x16x32_bf16(
            w2frag[t][1], h1frag[1], acc, 0, 0, 0);
        const f32x4 r = __builtin_elementwise_max(acc, zero4);
        p4 += r * w3v[t];
      }

      // fire-and-forget: no cross-lane ops in the pass chain
      obp[p * 16] = (p4[0] + p4[1]) + (p4[2] + p4[3]);
    }
  }

  __syncthreads();

  // ---- tail: sum 4 lane-group partials per (row, feature), store float4 ----
  {
    const int rr = tid;                    // one row per thread
    const f32x4 b3q = *reinterpret_cast<const f32x4*>(b3 + fg * kFPB);
    f32x4 v;
    #pragma unroll
    for (int w = 0; w < 4; ++w) {
      const float s0 = ob[w * 4 + 0][rr] + ob[w * 4 + 1][rr];
      const float s1 = ob[w * 4 + 2][rr] + ob[w * 4 + 3][rr];
      v[w] = s0 + s1 + b3q[w];
    }
    *reinterpret_cast<f32x4*>(out + (size_t)(r0 + rr) * kF + fg * kFPB) = v;
  }
}

}  // namespace

extern "C" void kernel_launch(void* const* d_in, const int* in_sizes, int n_in,
                              void* d_out, int out_size, void* d_ws, size_t ws_size,
                              hipStream_t stream) {
  const float* x  = (const float*)d_in[0];
  const float* w1 = (const float*)d_in[1];
  const float* b1 = (const float*)d_in[2];
  const float* w2 = (const float*)d_in[3];
  const float* b2 = (const float*)d_in[4];
  const float* w3 = (const float*)d_in[5];
  const float* b3 = (const float*)d_in[6];
  float* out = (float*)d_out;

  __bf16* w2p = (__bf16*)d_ws;            // 256*64*64*2 B = 2 MB

  hipLaunchKernelGGL(pack_w2, dim3(kF / 4), dim3(256), 0, stream, w2, w2p);
  hipLaunchKernelGGL(mlp_pf_v8, dim3(kBlocks), dim3(kThreads), 0, stream,
                     x, w1, b1, w2p, b2, w3, b3, out);
}

// Round 9
// 41.346 us; speedup vs baseline: 2.2600x; 2.2600x over previous
//
#include <hip/hip_runtime.h>
#include <hip/hip_bf16.h>

// MLP_small_per_feature: per-feature MLP 1 -> 64 -> 64 -> 1, F=256, B=8192.
// v9 = v7's proven body (43.2 us, no spills) + ILP fix:
//  - launch_bounds(256,3): v6/v5/v8 post-mortems prove tight VGPR caps cause
//    either spills (SGPR=96, FETCH~=WRITE~=170MB signature) or serialized
//    pass chains. (256,4)'s 64-VGPR squeeze gave neither ILP nor TLP.
//  - passes processed in PAIRS with independent register state; both x
//    values arrive in one ds_read_b64 (xs pass-major, stride 10 floats ->
//    conflict-free banks).
//  - w2 via packed bf16 fragment-major w2p in d_ws (L2-resident, coalesced).
//
// MFMA 16x16x32_bf16 layout (verified rounds 1-8, absmax 0.031):
//   A: row m = lane&15, k = (lane>>4)*8 + i
//   B: col n = lane&15, k = (lane>>4)*8 + i
//   C/D: col n = lane&15, row m = (lane>>4)*4 + r

namespace {

constexpr int kF = 256;
constexpr int kH = 64;
constexpr int kB = 8192;

constexpr int kFPB     = 4;               // features per block (one per wave)
constexpr int kRPB     = 128;             // rows per block
constexpr int kThreads = 256;             // 4 waves
constexpr int kFG      = kF / kFPB;       // 64 feature groups
constexpr int kRG      = kB / kRPB;       // 64 row groups
constexpr int kBlocks  = kFG * kRG;       // 4096
constexpr int kPasses  = kRPB / 16;       // 8
constexpr int kXP      = 10;              // xs pass-dim stride: l15*10%32 all distinct

using f32x2  = __attribute__((ext_vector_type(2))) float;
using f32x4  = __attribute__((ext_vector_type(4))) float;
using bf16x4 = __attribute__((ext_vector_type(4))) __bf16;
using bf16x8 = __attribute__((ext_vector_type(8))) __bf16;

// ---- prep: pack w2 (fp32 [F][64][64]) -> bf16 fragment-major ----
// w2p elem offset ((f*8 + t*2+ks)*64 + lane)*8; lane l's fragment (t,ks) =
// w2[f][o=t*16+(l&15)][ks*32+(l>>4)*8 .. +8].
__global__ __launch_bounds__(256)
void pack_w2(const float* __restrict__ w2, __bf16* __restrict__ w2p)
{
  const int wid  = (int)threadIdx.x >> 6;
  const int lane = (int)threadIdx.x & 63;
  const int f    = (int)blockIdx.x * 4 + wid;
  const int l15  = lane & 15;
  const int lg   = lane >> 4;

  const float* w2f = w2 + (size_t)f * (kH * kH);
  #pragma unroll
  for (int t = 0; t < 4; ++t) {
    const int o = t * 16 + l15;
    #pragma unroll
    for (int ks = 0; ks < 2; ++ks) {
      const float* p = w2f + o * kH + ks * 32 + lg * 8;
      const f32x4 lo = *reinterpret_cast<const f32x4*>(p);
      const f32x4 hi = *reinterpret_cast<const f32x4*>(p + 4);
      const bf16x8 v = __builtin_shufflevector(
          __builtin_convertvector(lo, bf16x4),
          __builtin_convertvector(hi, bf16x4), 0, 1, 2, 3, 4, 5, 6, 7);
      *reinterpret_cast<bf16x8*>(
          w2p + (((size_t)f * 8 + t * 2 + ks) * 64 + lane) * 8) = v;
    }
  }
}

__global__ __launch_bounds__(kThreads, 3)
void mlp_pf_v9(const float* __restrict__ x,
               const float* __restrict__ w1,
               const float* __restrict__ b1,
               const __bf16* __restrict__ w2p,
               const float* __restrict__ b2,
               const float* __restrict__ w3,
               const float* __restrict__ b3,
               float* __restrict__ out)
{
  __shared__ float xs[kFPB][16][kXP];     // 2.5 KB [feat][l15][pass]
  __shared__ float outb[kRPB][kFPB + 1];  // 2.56 KB (pad: conflict-free)

  const int tid  = (int)threadIdx.x;
  const int wid  = tid >> 6;
  const int lane = tid & 63;
  const int l15  = lane & 15;
  const int lg   = lane >> 4;

  const int fg = (int)blockIdx.x & (kFG - 1);  // consecutive blocks: same rows
  const int rg = (int)blockIdx.x >> 6;
  const int f  = fg * kFPB + wid;          // this wave's feature
  const int r0 = rg * kRPB;

  // ---- w2 fragments: 8 coalesced 16B loads/lane (L2-resident w2p) ----
  bf16x8 w2frag[4][2];
  {
    const __bf16* base = w2p + ((size_t)f * 8 * 64 + lane) * 8;
    #pragma unroll
    for (int t = 0; t < 4; ++t)
      #pragma unroll
      for (int ks = 0; ks < 2; ++ks)
        w2frag[t][ks] = *reinterpret_cast<const bf16x8*>(
            base + (size_t)(t * 2 + ks) * 64 * 8);
  }

  // ---- stage x tile (128 rows x 4 feats) -> pass-major LDS ----
  if (tid < kRPB) {
    const int rr = tid;
    const f32x4 v = *reinterpret_cast<const f32x4*>(
        x + (size_t)(r0 + rr) * kF + fg * kFPB);
    const int a = rr & 15, b = rr >> 4;
    xs[0][a][b] = v[0]; xs[1][a][b] = v[1];
    xs[2][a][b] = v[2]; xs[3][a][b] = v[3];
  }

  // ---- per-wave params (tiny, L1/L2-resident) ----
  f32x4 w1v[2][2], b1v[2][2];
  #pragma unroll
  for (int ks = 0; ks < 2; ++ks) {
    const float* pw = w1 + f * kH + ks * 32 + lg * 8;
    const float* pb = b1 + f * kH + ks * 32 + lg * 8;
    w1v[ks][0] = *reinterpret_cast<const f32x4*>(pw);
    w1v[ks][1] = *reinterpret_cast<const f32x4*>(pw + 4);
    b1v[ks][0] = *reinterpret_cast<const f32x4*>(pb);
    b1v[ks][1] = *reinterpret_cast<const f32x4*>(pb + 4);
  }
  f32x4 b2c[4], w3v[4];
  #pragma unroll
  for (int t = 0; t < 4; ++t) {
    b2c[t] = *reinterpret_cast<const f32x4*>(b2 + f * kH + t * 16 + lg * 4);
    w3v[t] = *reinterpret_cast<const f32x4*>(w3 + f * kH + t * 16 + lg * 4);
  }
  const float b3v = b3[f];

  __syncthreads();   // xs ready

  const f32x4 zero4 = {0.f, 0.f, 0.f, 0.f};
  float keep = 0.f;

  #pragma unroll
  for (int pp = 0; pp < kPasses / 2; ++pp) {
    // both passes' x values in one conflict-free ds_read_b64
    const f32x2 xp = *reinterpret_cast<const f32x2*>(&xs[wid][l15][2 * pp]);

    // ---- two independent pass-states: layer 1 for A and B ----
    bf16x8 h1A[2], h1B[2];
    #pragma unroll
    for (int ks = 0; ks < 2; ++ks) {
      f32x4 aA = w1v[ks][0] * xp[0] + b1v[ks][0];
      f32x4 bA = w1v[ks][1] * xp[0] + b1v[ks][1];
      f32x4 aB = w1v[ks][0] * xp[1] + b1v[ks][0];
      f32x4 bB = w1v[ks][1] * xp[1] + b1v[ks][1];
      aA = __builtin_elementwise_max(aA, zero4);
      bA = __builtin_elementwise_max(bA, zero4);
      aB = __builtin_elementwise_max(aB, zero4);
      bB = __builtin_elementwise_max(bB, zero4);
      h1A[ks] = __builtin_shufflevector(
          __builtin_convertvector(aA, bf16x4),
          __builtin_convertvector(bA, bf16x4), 0, 1, 2, 3, 4, 5, 6, 7);
      h1B[ks] = __builtin_shufflevector(
          __builtin_convertvector(aB, bf16x4),
          __builtin_convertvector(bB, bf16x4), 0, 1, 2, 3, 4, 5, 6, 7);
    }

    // ---- layer 2 + epilogue, A and B interleaved per o-tile ----
    f32x4 p4A = zero4, p4B = zero4;
    #pragma unroll
    for (int t = 0; t < 4; ++t) {
      f32x4 accA = __builtin_amdgcn_mfma_f32_16x16x32_bf16(
          w2frag[t][0], h1A[0], b2c[t], 0, 0, 0);
      f32x4 accB = __builtin_amdgcn_mfma_f32_16x16x32_bf16(
          w2frag[t][0], h1B[0], b2c[t], 0, 0, 0);
      accA = __builtin_amdgcn_mfma_f32_16x16x32_bf16(
          w2frag[t][1], h1A[1], accA, 0, 0, 0);
      accB = __builtin_amdgcn_mfma_f32_16x16x32_bf16(
          w2frag[t][1], h1B[1], accB, 0, 0, 0);
      const f32x4 rA = __builtin_elementwise_max(accA, zero4);
      const f32x4 rB = __builtin_elementwise_max(accB, zero4);
      p4A += rA * w3v[t];
      p4B += rB * w3v[t];
    }

    // ---- reductions for both passes (independent chains) ----
    float sA = (p4A[0] + p4A[1]) + (p4A[2] + p4A[3]);
    float sB = (p4B[0] + p4B[1]) + (p4B[2] + p4B[3]);
    sA += __shfl_xor(sA, 16);
    sB += __shfl_xor(sB, 16);
    sA += __shfl_xor(sA, 32);
    sB += __shfl_xor(sB, 32);

    // lane-group lg keeps pass (quad*4+lg); store once per 4 passes
    const int pA = 2 * pp, pB = 2 * pp + 1;
    keep = (lg == (pA & 3)) ? sA : keep;
    keep = (lg == (pB & 3)) ? sB : keep;
    if ((pB & 3) == 3) {
      outb[(pB >> 2) * 64 + lane][wid] = keep + b3v;
    }
  }

  __syncthreads();

  // ---- output: one float4 (4 features) per row ----
  if (tid < kRPB) {
    const int rr = tid;
    const f32x4 v = {outb[rr][0], outb[rr][1], outb[rr][2], outb[rr][3]};
    *reinterpret_cast<f32x4*>(out + (size_t)(r0 + rr) * kF + fg * kFPB) = v;
  }
}

}  // namespace

extern "C" void kernel_launch(void* const* d_in, const int* in_sizes, int n_in,
                              void* d_out, int out_size, void* d_ws, size_t ws_size,
                              hipStream_t stream) {
  const float* x  = (const float*)d_in[0];
  const float* w1 = (const float*)d_in[1];
  const float* b1 = (const float*)d_in[2];
  const float* w2 = (const float*)d_in[3];
  const float* b2 = (const float*)d_in[4];
  const float* w3 = (const float*)d_in[5];
  const float* b3 = (const float*)d_in[6];
  float* out = (float*)d_out;

  __bf16* w2p = (__bf16*)d_ws;            // 256*64*64*2 B = 2 MB

  hipLaunchKernelGGL(pack_w2, dim3(kF / 4), dim3(256), 0, stream, w2, w2p);
  hipLaunchKernelGGL(mlp_pf_v9, dim3(kBlocks), dim3(kThreads), 0, stream,
                     x, w1, b1, w2p, b2, w3, b3, out);
}